// Round 8
// baseline (77.839 us; speedup 1.0000x reference)
//
#include <hip/hip_runtime.h>
#include <math.h>

#define BB 64
#define TT 2048
#define DD 512
#define HH 512
#define NC 16                 // k1 chunks: CHUNK=128 rows/block, 1024 blocks
#define CHUNK (TT / NC)
#define TH 8.0f               // defer-rescale threshold

// ---------------------------------------------------------------------------
// async global->LDS 16B per lane: LDS dest = wave-uniform base + lane*16,
// global src = per-lane address. (guide §5 / common-mistake #1)
// ---------------------------------------------------------------------------
typedef unsigned int u32;
__device__ __forceinline__ void async_load16(const float* g, float* l) {
    __builtin_amdgcn_global_load_lds(
        (const __attribute__((address_space(1))) u32*)g,
        (__attribute__((address_space(3))) u32*)l,
        16, 0, 0);
}

// ---------------------------------------------------------------------------
// Kernel 1: fused scores + deferred-rescale online-softmax + partial context.
// grid (NC, B), block 256 (4 waves). Wave w owns 32 contiguous rows.
// Rows stream through a wave-private 4-slot LDS ring via global_load_lds;
// counted vmcnt(6) steady-state waits, no barriers in the main loop.
// ---------------------------------------------------------------------------
__global__ __launch_bounds__(256) void k1_partial(
    const float* __restrict__ x, const float* __restrict__ enc,
    const int* __restrict__ step_ptr,
    float* __restrict__ ws_m, float* __restrict__ ws_l, float* __restrict__ ws_c)
{
    const int chunk = blockIdx.x;
    const int b     = blockIdx.y;
    const int tid   = threadIdx.x;
    const int w     = tid >> 6;
    const int lane  = tid & 63;
    const int step  = *step_ptr;
    const int trow0 = chunk * CHUNK + w * 32;   // wave's first row (32 rows/wave)

    __shared__ float stage[4][4][DD];           // [wave][slot][512] = 32 KB
    __shared__ float ls_m[4], ls_l[4];
    __shared__ float ls_c[4][DD];               // 8 KB

    const float4* xr = (const float4*)(x + (size_t)b * DD);
    const float4 xa = xr[lane];
    const float4 xb = xr[64 + lane];
    // drain x loads so vmcnt counting below is exact
    asm volatile("s_waitcnt vmcnt(0)" ::: "memory");

    const float* gbase = enc + (size_t)b * TT * DD + (size_t)trow0 * DD;

    float m = -1e30f, l = 0.f;
    float4 ca = make_float4(0.f,0.f,0.f,0.f), cb = make_float4(0.f,0.f,0.f,0.f);

    // issue row r (2 DMA instrs: halves of 1 KB each) into slot r&3
    #define ISSUE(r) {                                              \
        const float* g_ = gbase + (r) * DD + lane * 4;              \
        float* d_ = &stage[w][(r) & 3][0];                          \
        async_load16(g_, d_);                                       \
        async_load16(g_ + 256, d_ + 256);                           \
    }
    // consume row r from its slot
    #define CONSUME(r) {                                            \
        const float* sp_ = &stage[w][(r) & 3][0];                   \
        const float4 ea = *(const float4*)&sp_[lane * 4];           \
        const float4 eb = *(const float4*)&sp_[256 + lane * 4];     \
        float s = ea.x*xa.x + ea.y*xa.y + ea.z*xa.z + ea.w*xa.w     \
                + eb.x*xb.x + eb.y*xb.y + eb.z*xb.z + eb.w*xb.w;    \
        _Pragma("unroll")                                           \
        for (int off = 32; off; off >>= 1) s += __shfl_xor(s, off, 64); \
        if (trow0 + (r) == step) s = -1e30f;                        \
        if (s > m + TH) {                                           \
            const float sc_ = __expf(m - s);                        \
            l *= sc_;                                               \
            ca.x *= sc_; ca.y *= sc_; ca.z *= sc_; ca.w *= sc_;     \
            cb.x *= sc_; cb.y *= sc_; cb.z *= sc_; cb.w *= sc_;     \
            m = s;                                                  \
        }                                                           \
        const float wgt = __expf(s - m);                            \
        l += wgt;                                                   \
        ca.x = fmaf(wgt, ea.x, ca.x); ca.y = fmaf(wgt, ea.y, ca.y); \
        ca.z = fmaf(wgt, ea.z, ca.z); ca.w = fmaf(wgt, ea.w, ca.w); \
        cb.x = fmaf(wgt, eb.x, cb.x); cb.y = fmaf(wgt, eb.y, cb.y); \
        cb.z = fmaf(wgt, eb.z, cb.z); cb.w = fmaf(wgt, eb.w, cb.w); \
    }

    // prologue: 3 rows in flight (6 outstanding)
    ISSUE(0); ISSUE(1); ISSUE(2);

    // steady state: issue row r+3 (8 outstanding), wait oldest row done (6)
    for (int r = 0; r < 29; ++r) {
        ISSUE(r + 3);
        asm volatile("s_waitcnt vmcnt(6)" ::: "memory");
        CONSUME(r);
    }
    asm volatile("s_waitcnt vmcnt(4)" ::: "memory");
    CONSUME(29);
    asm volatile("s_waitcnt vmcnt(2)" ::: "memory");
    CONSUME(30);
    asm volatile("s_waitcnt vmcnt(0)" ::: "memory");
    CONSUME(31);

    #undef ISSUE
    #undef CONSUME

    // ---- block combine of the 4 wave-partials via LDS ----
    if (lane == 0) { ls_m[w] = m; ls_l[w] = l; }
    {
        float* cw = ls_c[w];
        const int d0 = lane * 4;
        cw[d0 + 0] = ca.x; cw[d0 + 1] = ca.y; cw[d0 + 2] = ca.z; cw[d0 + 3] = ca.w;
        cw[256 + d0 + 0] = cb.x; cw[256 + d0 + 1] = cb.y;
        cw[256 + d0 + 2] = cb.z; cw[256 + d0 + 3] = cb.w;
    }
    __syncthreads();

    const float M = fmaxf(fmaxf(ls_m[0], ls_m[1]), fmaxf(ls_m[2], ls_m[3]));
    const float f0 = __expf(ls_m[0] - M);
    const float f1 = __expf(ls_m[1] - M);
    const float f2 = __expf(ls_m[2] - M);
    const float f3 = __expf(ls_m[3] - M);
    const float L = ls_l[0] * f0 + ls_l[1] * f1 + ls_l[2] * f2 + ls_l[3] * f3;

    const int bc = b * NC + chunk;
    for (int d = tid; d < DD; d += 256) {
        const float v = ls_c[0][d] * f0 + ls_c[1][d] * f1
                      + ls_c[2][d] * f2 + ls_c[3][d] * f3;
        ws_c[(size_t)bc * DD + d] = v;
    }
    if (tid == 0) { ws_m[bc] = M; ws_l[bc] = L; }
}

// ---------------------------------------------------------------------------
// Kernel 1b: merge NC partials -> normalized context ctx[B][DD].
// grid (B, 2): block (b, half) handles 256 d -> 128 blocks.
// ---------------------------------------------------------------------------
__global__ __launch_bounds__(256) void k1b_merge(
    const float* __restrict__ ws_m, const float* __restrict__ ws_l,
    const float* __restrict__ ws_c, float* __restrict__ ctx)
{
    const int b    = blockIdx.x;
    const int half = blockIdx.y;
    const int tid  = threadIdx.x;
    __shared__ float fac[NC];

    float M = -1e30f;
    #pragma unroll
    for (int i = 0; i < NC; ++i) M = fmaxf(M, ws_m[b * NC + i]);
    float L = 0.f;
    #pragma unroll
    for (int i = 0; i < NC; ++i) L += ws_l[b * NC + i] * __expf(ws_m[b * NC + i] - M);
    const float inv = 1.f / L;
    if (tid < NC) fac[tid] = __expf(ws_m[b * NC + tid] - M) * inv;
    __syncthreads();

    const int d = half * 256 + tid;
    float acc = 0.f;
    #pragma unroll
    for (int i = 0; i < NC; ++i)
        acc = fmaf(ws_c[(size_t)(b * NC + i) * DD + d], fac[i], acc);
    ctx[(size_t)b * DD + d] = acc;
}

// ---------------------------------------------------------------------------
// Kernel 2: gated gemm with 8-b W reuse.
// grid (16, 8): block covers 8 float4-cols (32 h) x 8 b.
// concat in LDS: padded-segment layout, bijective:
//   cidx(k,bb) = (k>>5)*260 + (k&31)*8 + bb
// ---------------------------------------------------------------------------
#define COLS 8
__device__ __forceinline__ int cidx(int k, int bb) {
    return (k >> 5) * 260 + (k & 31) * 8 + bb;
}

__global__ __launch_bounds__(256) void k2_gemm(
    const float* __restrict__ x, const float* __restrict__ ctx,
    const float* __restrict__ W, const float* __restrict__ bias,
    float* __restrict__ out)
{
    const int g   = blockIdx.x;     // 0..15
    const int bg  = blockIdx.y;     // 0..7
    const int tid = threadIdx.x;

    __shared__ float  con[32 * 260];        // 8320 floats, padded segments
    __shared__ float4 part[4][COLS][8];

    const float4* x4 = (const float4*)x;
    const float4* c4 = (const float4*)ctx;

    for (int idx = tid; idx < 2048; idx += 256) {
        const int bb = idx >> 8, k4 = idx & 255;
        const int b  = bg * 8 + bb;
        const float4 v = (k4 < 128) ? x4[(size_t)b * 128 + k4]
                                    : c4[(size_t)b * 128 + (k4 - 128)];
        const int k = k4 * 4;
        con[cidx(k + 0, bb)] = v.x;
        con[cidx(k + 1, bb)] = v.y;
        con[cidx(k + 2, bb)] = v.z;
        con[cidx(k + 3, bb)] = v.w;
    }
    __syncthreads();

    const int cl   = tid & 7;               // col within block
    const int kseg = tid >> 3;              // 0..31, 32 k each
    const int col4 = g * COLS + cl;
    const float4* Wp = (const float4*)W + (size_t)(kseg * 32) * 128 + col4;

    float4 acc[8];
    #pragma unroll
    for (int bb = 0; bb < 8; ++bb) acc[bb] = make_float4(0.f,0.f,0.f,0.f);

    #pragma unroll 4
    for (int kk = 0; kk < 32; ++kk) {
        const float4 wv = Wp[(size_t)kk * 128];
        const int k = kseg * 32 + kk;
        const float4 c0 = *(const float4*)&con[cidx(k, 0)];   // bb 0..3
        const float4 c1 = *(const float4*)&con[cidx(k, 4)];   // bb 4..7
        const float cv[8] = {c0.x, c0.y, c0.z, c0.w, c1.x, c1.y, c1.z, c1.w};
        #pragma unroll
        for (int bb = 0; bb < 8; ++bb) {
            acc[bb].x = fmaf(cv[bb], wv.x, acc[bb].x);
            acc[bb].y = fmaf(cv[bb], wv.y, acc[bb].y);
            acc[bb].z = fmaf(cv[bb], wv.z, acc[bb].z);
            acc[bb].w = fmaf(cv[bb], wv.w, acc[bb].w);
        }
    }

    // in-wave reduce over the 8 ksegs resident in each wave (lane = kseg*8+cl)
    #pragma unroll
    for (int off = 8; off <= 32; off <<= 1) {
        #pragma unroll
        for (int bb = 0; bb < 8; ++bb) {
            acc[bb].x += __shfl_xor(acc[bb].x, off, 64);
            acc[bb].y += __shfl_xor(acc[bb].y, off, 64);
            acc[bb].z += __shfl_xor(acc[bb].z, off, 64);
            acc[bb].w += __shfl_xor(acc[bb].w, off, 64);
        }
    }
    const int wv_ = tid >> 6, lane = tid & 63;
    if (lane < 8) {
        #pragma unroll
        for (int bb = 0; bb < 8; ++bb) part[wv_][lane][bb] = acc[bb];
    }
    __syncthreads();

    if (tid < 64) {
        const int bb = tid >> 3, cl2 = tid & 7;
        float4 r = part[0][cl2][bb];
        #pragma unroll
        for (int ww = 1; ww < 4; ++ww) {
            const float4 p = part[ww][cl2][bb];
            r.x += p.x; r.y += p.y; r.z += p.z; r.w += p.w;
        }
        const int c4i = g * COLS + cl2;
        const int h   = c4i * 4;
        const int b   = bg * 8 + bb;
        const float4 bv = ((const float4*)bias)[c4i];
        const float xv0 = con[cidx(h + 0, bb)];
        const float xv1 = con[cidx(h + 1, bb)];
        const float xv2 = con[cidx(h + 2, bb)];
        const float xv3 = con[cidx(h + 3, bb)];
        float4 o;
        o.x = xv0 / (1.f + __expf(-(r.x + bv.x)));
        o.y = xv1 / (1.f + __expf(-(r.y + bv.y)));
        o.z = xv2 / (1.f + __expf(-(r.z + bv.z)));
        o.w = xv3 / (1.f + __expf(-(r.w + bv.w)));
        ((float4*)out)[(size_t)b * 128 + c4i] = o;
    }
}

// ---------------------------------------------------------------------------
extern "C" void kernel_launch(void* const* d_in, const int* in_sizes, int n_in,
                              void* d_out, int out_size, void* d_ws, size_t ws_size,
                              hipStream_t stream) {
    const float* x    = (const float*)d_in[0];
    const float* enc  = (const float*)d_in[1];
    const float* W    = (const float*)d_in[2];
    const float* bias = (const float*)d_in[3];
    const int*   step = (const int*)d_in[4];
    float* out = (float*)d_out;
    float* ws  = (float*)d_ws;

    float* ws_m = ws;                                 // [B*NC]
    float* ws_l = ws_m + (size_t)BB * NC;             // [B*NC]
    float* ws_c = ws_l + (size_t)BB * NC;             // [B*NC*DD]
    float* ctx  = ws_c + (size_t)BB * NC * DD;        // [B*DD]

    k1_partial<<<dim3(NC, BB), 256, 0, stream>>>(x, enc, step, ws_m, ws_l, ws_c);
    k1b_merge<<<dim3(BB, 2), 256, 0, stream>>>(ws_m, ws_l, ws_c, ctx);
    k2_gemm<<<dim3(16, 8), 256, 0, stream>>>(x, ctx, W, bias, out);
}

// Round 9
// 58.057 us; speedup vs baseline: 1.3407x; 1.3407x over previous
//
#include <hip/hip_runtime.h>
#include <math.h>

#define BB 64
#define TT 2048
#define DD 512
#define HH 512
#define NC 16                 // k1 chunks: CHUNK=128 rows/block, 1024 blocks
#define CHUNK (TT / NC)
#define TH 8.0f               // defer-rescale threshold

typedef float f32x4 __attribute__((ext_vector_type(4)));
__device__ __forceinline__ float4 ntload4(const float4* p) {
    union { f32x4 v; float4 f; } u;
    u.v = __builtin_nontemporal_load((const f32x4*)p);
    return u.f;
}

// ---------------------------------------------------------------------------
// Kernel 1: fused scores + deferred-rescale online-softmax + partial context.
// grid (NC, B), block 256 (4 waves). Wave w owns 32 contiguous rows,
// processed as 8 batches of 4 rows with one-batch-ahead prefetch.
// enc reads are non-temporal (zero reuse -> don't allocate in L2).
// [R5-verified best: 58.7 us total, k1 ~5.0 TB/s effective read]
// ---------------------------------------------------------------------------
__global__ __launch_bounds__(256) void k1_partial(
    const float* __restrict__ x, const float* __restrict__ enc,
    const int* __restrict__ step_ptr,
    float* __restrict__ ws_m, float* __restrict__ ws_l, float* __restrict__ ws_c)
{
    const int chunk = blockIdx.x;
    const int b     = blockIdx.y;
    const int tid   = threadIdx.x;
    const int w     = tid >> 6;
    const int lane  = tid & 63;
    const int step  = *step_ptr;
    const int trow0 = chunk * CHUNK + w * 32;   // wave's first row (32 rows/wave)

    const float4* xr = (const float4*)(x + (size_t)b * DD);
    const float4 xa = xr[lane];
    const float4 xb = xr[64 + lane];

    // row r in 0..31: halfA rp[r*128], halfB rp[r*128+64]
    const float4* __restrict__ rp =
        (const float4*)(enc + (size_t)b * TT * DD) + (size_t)trow0 * 128 + lane;

    float m = -1e30f, l = 0.f;
    float4 ca = make_float4(0.f,0.f,0.f,0.f), cb = make_float4(0.f,0.f,0.f,0.f);

    float4 A[2][4], Bv[2][4];
    #pragma unroll
    for (int k = 0; k < 4; ++k) {
        A[0][k]  = ntload4(rp + k * 128);
        Bv[0][k] = ntload4(rp + k * 128 + 64);
    }

    #pragma unroll
    for (int j = 0; j < 8; ++j) {              // fully unrolled: static indices
        const int cur = j & 1, nx = cur ^ 1;
        if (j < 7) {                           // prefetch next batch (8-load clause)
            #pragma unroll
            for (int k = 0; k < 4; ++k) {
                A[nx][k]  = ntload4(rp + ((j + 1) * 4 + k) * 128);
                Bv[nx][k] = ntload4(rp + ((j + 1) * 4 + k) * 128 + 64);
            }
        }
        // 4 independent dot products
        float s[4];
        #pragma unroll
        for (int k = 0; k < 4; ++k) {
            const float4 ea = A[cur][k], eb = Bv[cur][k];
            s[k] = ea.x*xa.x + ea.y*xa.y + ea.z*xa.z + ea.w*xa.w
                 + eb.x*xb.x + eb.y*xb.y + eb.z*xb.z + eb.w*xb.w;
        }
        // 4 interleaved wave reductions
        #pragma unroll
        for (int off = 32; off; off >>= 1) {
            #pragma unroll
            for (int k = 0; k < 4; ++k) s[k] += __shfl_xor(s[k], off, 64);
        }
        // mask current step (t uniform per k across lanes)
        #pragma unroll
        for (int k = 0; k < 4; ++k)
            if (trow0 + j * 4 + k == step) s[k] = -1e30f;

        // one amortized, wave-uniform rescale check per batch
        const float bm = fmaxf(fmaxf(s[0], s[1]), fmaxf(s[2], s[3]));
        if (bm > m + TH) {
            const float sc = __expf(m - bm);
            l *= sc;
            ca.x *= sc; ca.y *= sc; ca.z *= sc; ca.w *= sc;
            cb.x *= sc; cb.y *= sc; cb.z *= sc; cb.w *= sc;
            m = bm;
        }
        float wk[4];
        #pragma unroll
        for (int k = 0; k < 4; ++k) wk[k] = __expf(s[k] - m);  // masked row -> 0
        l += (wk[0] + wk[1]) + (wk[2] + wk[3]);
        #pragma unroll
        for (int k = 0; k < 4; ++k) {
            ca.x = fmaf(wk[k], A[cur][k].x, ca.x);
            ca.y = fmaf(wk[k], A[cur][k].y, ca.y);
            ca.z = fmaf(wk[k], A[cur][k].z, ca.z);
            ca.w = fmaf(wk[k], A[cur][k].w, ca.w);
            cb.x = fmaf(wk[k], Bv[cur][k].x, cb.x);
            cb.y = fmaf(wk[k], Bv[cur][k].y, cb.y);
            cb.z = fmaf(wk[k], Bv[cur][k].z, cb.z);
            cb.w = fmaf(wk[k], Bv[cur][k].w, cb.w);
        }
    }

    // ---- block combine of the 4 wave-partials via LDS ----
    __shared__ float ls_m[4], ls_l[4];
    __shared__ float ls_c[4][DD];
    if (lane == 0) { ls_m[w] = m; ls_l[w] = l; }
    {
        float* cw = ls_c[w];
        const int d0 = lane * 4;
        cw[d0 + 0] = ca.x; cw[d0 + 1] = ca.y; cw[d0 + 2] = ca.z; cw[d0 + 3] = ca.w;
        cw[256 + d0 + 0] = cb.x; cw[256 + d0 + 1] = cb.y;
        cw[256 + d0 + 2] = cb.z; cw[256 + d0 + 3] = cb.w;
    }
    __syncthreads();

    const float M = fmaxf(fmaxf(ls_m[0], ls_m[1]), fmaxf(ls_m[2], ls_m[3]));
    const float f0 = __expf(ls_m[0] - M);
    const float f1 = __expf(ls_m[1] - M);
    const float f2 = __expf(ls_m[2] - M);
    const float f3 = __expf(ls_m[3] - M);
    const float L = ls_l[0] * f0 + ls_l[1] * f1 + ls_l[2] * f2 + ls_l[3] * f3;

    const int bc = b * NC + chunk;
    for (int d = tid; d < DD; d += 256) {
        const float v = ls_c[0][d] * f0 + ls_c[1][d] * f1
                      + ls_c[2][d] * f2 + ls_c[3][d] * f3;
        ws_c[(size_t)bc * DD + d] = v;
    }
    if (tid == 0) { ws_m[bc] = M; ws_l[bc] = L; }
}

// ---------------------------------------------------------------------------
// Kernel 1b: merge NC partials -> normalized context ctx[B][DD].
// grid (B, 2): block (b, half) handles 256 d -> 128 blocks.
// ---------------------------------------------------------------------------
__global__ __launch_bounds__(256) void k1b_merge(
    const float* __restrict__ ws_m, const float* __restrict__ ws_l,
    const float* __restrict__ ws_c, float* __restrict__ ctx)
{
    const int b    = blockIdx.x;
    const int half = blockIdx.y;
    const int tid  = threadIdx.x;
    __shared__ float fac[NC];

    float M = -1e30f;
    #pragma unroll
    for (int i = 0; i < NC; ++i) M = fmaxf(M, ws_m[b * NC + i]);
    float L = 0.f;
    #pragma unroll
    for (int i = 0; i < NC; ++i) L += ws_l[b * NC + i] * __expf(ws_m[b * NC + i] - M);
    const float inv = 1.f / L;
    if (tid < NC) fac[tid] = __expf(ws_m[b * NC + tid] - M) * inv;
    __syncthreads();

    const int d = half * 256 + tid;
    float acc = 0.f;
    #pragma unroll
    for (int i = 0; i < NC; ++i)
        acc = fmaf(ws_c[(size_t)(b * NC + i) * DD + d], fac[i], acc);
    ctx[(size_t)b * DD + d] = acc;
}

// ---------------------------------------------------------------------------
// Kernel 2: gated gemm with 8-b W reuse.
// grid (16, 8): block covers 8 float4-cols (32 h) x 8 b.
// concat in LDS: padded-segment layout, bijective:
//   cidx(k,bb) = (k>>5)*260 + (k&31)*8 + bb
// ---------------------------------------------------------------------------
#define COLS 8
__device__ __forceinline__ int cidx(int k, int bb) {
    return (k >> 5) * 260 + (k & 31) * 8 + bb;
}

__global__ __launch_bounds__(256) void k2_gemm(
    const float* __restrict__ x, const float* __restrict__ ctx,
    const float* __restrict__ W, const float* __restrict__ bias,
    float* __restrict__ out)
{
    const int g   = blockIdx.x;     // 0..15
    const int bg  = blockIdx.y;     // 0..7
    const int tid = threadIdx.x;

    __shared__ float  con[32 * 260];        // 8320 floats, padded segments
    __shared__ float4 part[4][COLS][8];

    const float4* x4 = (const float4*)x;
    const float4* c4 = (const float4*)ctx;

    for (int idx = tid; idx < 2048; idx += 256) {
        const int bb = idx >> 8, k4 = idx & 255;
        const int b  = bg * 8 + bb;
        const float4 v = (k4 < 128) ? x4[(size_t)b * 128 + k4]
                                    : c4[(size_t)b * 128 + (k4 - 128)];
        const int k = k4 * 4;
        con[cidx(k + 0, bb)] = v.x;
        con[cidx(k + 1, bb)] = v.y;
        con[cidx(k + 2, bb)] = v.z;
        con[cidx(k + 3, bb)] = v.w;
    }
    __syncthreads();

    const int cl   = tid & 7;               // col within block
    const int kseg = tid >> 3;              // 0..31, 32 k each
    const int col4 = g * COLS + cl;
    const float4* Wp = (const float4*)W + (size_t)(kseg * 32) * 128 + col4;

    float4 acc[8];
    #pragma unroll
    for (int bb = 0; bb < 8; ++bb) acc[bb] = make_float4(0.f,0.f,0.f,0.f);

    #pragma unroll 4
    for (int kk = 0; kk < 32; ++kk) {
        const float4 wv = Wp[(size_t)kk * 128];
        const int k = kseg * 32 + kk;
        const float4 c0 = *(const float4*)&con[cidx(k, 0)];   // bb 0..3
        const float4 c1 = *(const float4*)&con[cidx(k, 4)];   // bb 4..7
        const float cv[8] = {c0.x, c0.y, c0.z, c0.w, c1.x, c1.y, c1.z, c1.w};
        #pragma unroll
        for (int bb = 0; bb < 8; ++bb) {
            acc[bb].x = fmaf(cv[bb], wv.x, acc[bb].x);
            acc[bb].y = fmaf(cv[bb], wv.y, acc[bb].y);
            acc[bb].z = fmaf(cv[bb], wv.z, acc[bb].z);
            acc[bb].w = fmaf(cv[bb], wv.w, acc[bb].w);
        }
    }

    // in-wave reduce over the 8 ksegs resident in each wave (lane = kseg*8+cl)
    #pragma unroll
    for (int off = 8; off <= 32; off <<= 1) {
        #pragma unroll
        for (int bb = 0; bb < 8; ++bb) {
            acc[bb].x += __shfl_xor(acc[bb].x, off, 64);
            acc[bb].y += __shfl_xor(acc[bb].y, off, 64);
            acc[bb].z += __shfl_xor(acc[bb].z, off, 64);
            acc[bb].w += __shfl_xor(acc[bb].w, off, 64);
        }
    }
    const int wv_ = tid >> 6, lane = tid & 63;
    if (lane < 8) {
        #pragma unroll
        for (int bb = 0; bb < 8; ++bb) part[wv_][lane][bb] = acc[bb];
    }
    __syncthreads();

    if (tid < 64) {
        const int bb = tid >> 3, cl2 = tid & 7;
        float4 r = part[0][cl2][bb];
        #pragma unroll
        for (int ww = 1; ww < 4; ++ww) {
            const float4 p = part[ww][cl2][bb];
            r.x += p.x; r.y += p.y; r.z += p.z; r.w += p.w;
        }
        const int c4i = g * COLS + cl2;
        const int h   = c4i * 4;
        const int b   = bg * 8 + bb;
        const float4 bv = ((const float4*)bias)[c4i];
        const float xv0 = con[cidx(h + 0, bb)];
        const float xv1 = con[cidx(h + 1, bb)];
        const float xv2 = con[cidx(h + 2, bb)];
        const float xv3 = con[cidx(h + 3, bb)];
        float4 o;
        o.x = xv0 / (1.f + __expf(-(r.x + bv.x)));
        o.y = xv1 / (1.f + __expf(-(r.y + bv.y)));
        o.z = xv2 / (1.f + __expf(-(r.z + bv.z)));
        o.w = xv3 / (1.f + __expf(-(r.w + bv.w)));
        ((float4*)out)[(size_t)b * 128 + c4i] = o;
    }
}

// ---------------------------------------------------------------------------
extern "C" void kernel_launch(void* const* d_in, const int* in_sizes, int n_in,
                              void* d_out, int out_size, void* d_ws, size_t ws_size,
                              hipStream_t stream) {
    const float* x    = (const float*)d_in[0];
    const float* enc  = (const float*)d_in[1];
    const float* W    = (const float*)d_in[2];
    const float* bias = (const float*)d_in[3];
    const int*   step = (const int*)d_in[4];
    float* out = (float*)d_out;
    float* ws  = (float*)d_ws;

    float* ws_m = ws;                                 // [B*NC]
    float* ws_l = ws_m + (size_t)BB * NC;             // [B*NC]
    float* ws_c = ws_l + (size_t)BB * NC;             // [B*NC*DD]
    float* ctx  = ws_c + (size_t)BB * NC * DD;        // [B*DD]

    k1_partial<<<dim3(NC, BB), 256, 0, stream>>>(x, enc, step, ws_m, ws_l, ws_c);
    k1b_merge<<<dim3(BB, 2), 256, 0, stream>>>(ws_m, ws_l, ws_c, ctx);
    k2_gemm<<<dim3(16, 8), 256, 0, stream>>>(x, ctx, W, bias, out);
}